// Round 1
// baseline (1170.677 us; speedup 1.0000x reference)
//
#include <hip/hip_runtime.h>
#include <hip/hip_bf16.h>
#include <cstdint>

#define BB 128
#define LL 28
#define FF 28
#define DM 256
#define DI 512
#define DS 16
#define DR 16
#define KK 3
#define NLAYER 5
#define NOUT 10
#define NTOK (BB * LL)   // 3584

__device__ __forceinline__ float sigmoidf_(float x) { return 1.0f / (1.0f + __expf(-x)); }
__device__ __forceinline__ float siluf_(float x) { return x * sigmoidf_(x); }
__device__ __forceinline__ float softplusf_(float x) {
    // matches jax.nn.softplus = log1p(exp(x)) with large-x guard
    return (x > 20.0f) ? x : log1pf(expf(x));
}

// C[M,N] = epilogue( A[M,lda(>=K)] @ W[N,K]^T )
// EPI 0: C = AB
// EPI 1: C = softplus(AB + bias[n])
// EPI 2: C = C + AB   (residual accumulate, in-place on C)
template <int EPI>
__global__ void gemm_nt(const float* __restrict__ A, int lda,
                        const float* __restrict__ W,
                        const float* __restrict__ bias,
                        float* __restrict__ C,
                        int M, int N, int K) {
    __shared__ float As[32][33];
    __shared__ float Ws[32][33];
    const int bm = blockIdx.y * 32;
    const int bn = blockIdx.x * 32;
    const int tid = threadIdx.x;          // 0..255
    const int lr = tid >> 3;              // 0..31
    const int lc = (tid & 7) * 4;         // 0,4,...,28
    const int tx = tid & 15;              // 0..15
    const int ty = tid >> 4;              // 0..15

    float acc00 = 0.f, acc01 = 0.f, acc10 = 0.f, acc11 = 0.f;

    for (int k0 = 0; k0 < K; k0 += 32) {
        #pragma unroll
        for (int j = 0; j < 4; ++j) {
            int k = k0 + lc + j;
            int m = bm + lr;
            As[lr][lc + j] = (m < M && k < K) ? A[(size_t)m * lda + k] : 0.f;
            int n = bn + lr;
            Ws[lr][lc + j] = (n < N && k < K) ? W[(size_t)n * K + k] : 0.f;
        }
        __syncthreads();
        #pragma unroll
        for (int kk = 0; kk < 32; ++kk) {
            float a0 = As[ty * 2 + 0][kk];
            float a1 = As[ty * 2 + 1][kk];
            float w0 = Ws[tx * 2 + 0][kk];
            float w1 = Ws[tx * 2 + 1][kk];
            acc00 += a0 * w0; acc01 += a0 * w1;
            acc10 += a1 * w0; acc11 += a1 * w1;
        }
        __syncthreads();
    }

    float accs[2][2] = {{acc00, acc01}, {acc10, acc11}};
    #pragma unroll
    for (int i = 0; i < 2; ++i) {
        #pragma unroll
        for (int j = 0; j < 2; ++j) {
            int m = bm + ty * 2 + i;
            int n = bn + tx * 2 + j;
            if (m < M && n < N) {
                float v = accs[i][j];
                if (EPI == 1) v = softplusf_(v + bias[n]);
                if (EPI == 2) v = v + C[(size_t)m * N + n];
                C[(size_t)m * N + n] = v;
            }
        }
    }
}

// u[m, di] = silu( causal_depthwise_conv3(xb)[m,di] + cb[di] )
// xb = xz[:, 0:DI] of xz[NTOK, 2*DI]
__global__ void conv_silu_kernel(const float* __restrict__ xz,
                                 const float* __restrict__ cw,   // [DI, K]
                                 const float* __restrict__ cb,   // [DI]
                                 float* __restrict__ u) {
    int idx = blockIdx.x * 256 + threadIdx.x;   // over NTOK*DI
    if (idx >= NTOK * DI) return;
    int di = idx & (DI - 1);
    int m = idx >> 9;                 // b*LL + l
    int l = m % LL;
    int b = m / LL;
    float acc = cb[di];
    #pragma unroll
    for (int k = 0; k < KK; ++k) {
        int lsrc = l + k - (KK - 1);
        if (lsrc >= 0) {
            acc += xz[(size_t)(b * LL + lsrc) * (2 * DI) + di] * cw[di * KK + k];
        }
    }
    u[(size_t)m * DI + di] = siluf_(acc);
}

// Selective scan: 1 block per batch element, 1 thread per channel di.
// Fuses  y = (scan_y + u*D) * silu(z)  epilogue.
__global__ void scan_kernel(const float* __restrict__ delta,   // [NTOK, DI]
                            const float* __restrict__ u,       // [NTOK, DI]
                            const float* __restrict__ dbc,     // [NTOK, DR+2*DS]
                            const float* __restrict__ xz,      // [NTOK, 2*DI] (z = cols DI..2DI)
                            const float* __restrict__ A_log,   // [DI, DS]
                            const float* __restrict__ Dv,      // [DI]
                            float* __restrict__ y) {           // [NTOK, DI]
    const int b = blockIdx.x;      // 0..BB-1
    const int di = threadIdx.x;    // 0..DI-1

    float A[DS], st[DS];
    #pragma unroll
    for (int s = 0; s < DS; ++s) {
        A[s] = -expf(A_log[di * DS + s]);
        st[s] = 0.f;
    }
    const float Dd = Dv[di];

    __shared__ float Bs[DS], Cs[DS];

    for (int l = 0; l < LL; ++l) {
        const int m = b * LL + l;
        if (di < DS) Bs[di] = dbc[(size_t)m * (DR + 2 * DS) + DR + di];
        else if (di < 2 * DS) Cs[di - DS] = dbc[(size_t)m * (DR + 2 * DS) + DR + DS + (di - DS)];
        __syncthreads();

        const float d = delta[(size_t)m * DI + di];
        const float uu = u[(size_t)m * DI + di];
        const float du = d * uu;
        float yv = 0.f;
        #pragma unroll
        for (int s = 0; s < DS; ++s) {
            st[s] = expf(d * A[s]) * st[s] + du * Bs[s];
            yv += st[s] * Cs[s];
        }
        const float zz = xz[(size_t)m * (2 * DI) + DI + di];
        y[(size_t)m * DI + di] = (yv + uu * Dd) * siluf_(zz);
        __syncthreads();
    }
}

// pooled[b,:] = mean_l h[b,l,:];  out[b,o] = pooled[b,:] @ cls[o,:]
__global__ void pool_classifier_kernel(const float* __restrict__ h,   // [NTOK, DM]
                                       const float* __restrict__ cls, // [NOUT, DM]
                                       float* __restrict__ out) {     // [BB, NOUT]
    const int b = blockIdx.x;
    const int dm = threadIdx.x;   // 0..255
    __shared__ float pool[DM];
    float p = 0.f;
    for (int l = 0; l < LL; ++l) p += h[(size_t)(b * LL + l) * DM + dm];
    pool[dm] = p * (1.0f / LL);
    __syncthreads();
    if (dm < NOUT) {
        float acc = 0.f;
        for (int k = 0; k < DM; ++k) acc += pool[k] * cls[dm * DM + k];
        out[b * NOUT + dm] = acc;
    }
}

extern "C" void kernel_launch(void* const* d_in, const int* in_sizes, int n_in,
                              void* d_out, int out_size, void* d_ws, size_t ws_size,
                              hipStream_t stream) {
    const float* x       = (const float*)d_in[0];   // [B,1,L,F] = [3584, 28]
    const float* ipw     = (const float*)d_in[1];   // [DM, F]
    const float* inw     = (const float*)d_in[2];   // [NL, 2*DI, DM]
    const float* convw   = (const float*)d_in[3];   // [NL, DI, K]
    const float* convb   = (const float*)d_in[4];   // [NL, DI]
    const float* xpw     = (const float*)d_in[5];   // [NL, DR+2DS, DI]
    const float* dtw     = (const float*)d_in[6];   // [NL, DI, DR]
    const float* dtb     = (const float*)d_in[7];   // [NL, DI]
    const float* alog    = (const float*)d_in[8];   // [NL, DI, DS]
    const float* Dvec    = (const float*)d_in[9];   // [NL, DI]
    const float* opw     = (const float*)d_in[10];  // [NL, DM, DI]
    const float* clsw    = (const float*)d_in[11];  // [OUT, DM]
    float* out = (float*)d_out;

    float* ws = (float*)d_ws;
    float* h     = ws;                      // NTOK*DM     = 917504
    float* xz    = h + (size_t)NTOK * DM;   // NTOK*2*DI   = 3670016
    float* u     = xz + (size_t)NTOK * 2 * DI;  // NTOK*DI = 1835008
    float* dbc   = u + (size_t)NTOK * DI;   // NTOK*48     = 172032
    float* delta = dbc + (size_t)NTOK * (DR + 2 * DS);  // NTOK*DI
    float* y     = delta + (size_t)NTOK * DI;           // NTOK*DI

    dim3 blk(256);

    // input projection: h = x @ ipw^T   (M=3584, N=256, K=28)
    {
        dim3 grid((DM + 31) / 32, (NTOK + 31) / 32);
        hipLaunchKernelGGL((gemm_nt<0>), grid, blk, 0, stream,
                           x, FF, ipw, nullptr, h, NTOK, DM, FF);
    }

    for (int layer = 0; layer < NLAYER; ++layer) {
        const float* inw_l   = inw  + (size_t)layer * 2 * DI * DM;
        const float* convw_l = convw + (size_t)layer * DI * KK;
        const float* convb_l = convb + (size_t)layer * DI;
        const float* xpw_l   = xpw  + (size_t)layer * (DR + 2 * DS) * DI;
        const float* dtw_l   = dtw  + (size_t)layer * DI * DR;
        const float* dtb_l   = dtb  + (size_t)layer * DI;
        const float* alog_l  = alog + (size_t)layer * DI * DS;
        const float* Dvec_l  = Dvec + (size_t)layer * DI;
        const float* opw_l   = opw  + (size_t)layer * DM * DI;

        // xz = h @ inw^T   (M=3584, N=1024, K=256)
        {
            dim3 grid((2 * DI + 31) / 32, (NTOK + 31) / 32);
            hipLaunchKernelGGL((gemm_nt<0>), grid, blk, 0, stream,
                               h, DM, inw_l, nullptr, xz, NTOK, 2 * DI, DM);
        }
        // u = silu(conv(xb) + cb)
        {
            dim3 grid((NTOK * DI) / 256);
            hipLaunchKernelGGL(conv_silu_kernel, grid, blk, 0, stream,
                               xz, convw_l, convb_l, u);
        }
        // dbc = u @ xpw^T   (M=3584, N=48, K=512)
        {
            dim3 grid((DR + 2 * DS + 31) / 32, (NTOK + 31) / 32);
            hipLaunchKernelGGL((gemm_nt<0>), grid, blk, 0, stream,
                               u, DI, xpw_l, nullptr, dbc, NTOK, DR + 2 * DS, DI);
        }
        // delta = softplus(dbc[:, :DR] @ dtw^T + dtb)   (M=3584, N=512, K=16)
        {
            dim3 grid((DI + 31) / 32, (NTOK + 31) / 32);
            hipLaunchKernelGGL((gemm_nt<1>), grid, blk, 0, stream,
                               dbc, DR + 2 * DS, dtw_l, dtb_l, delta, NTOK, DI, DR);
        }
        // selective scan + gate epilogue -> y
        {
            hipLaunchKernelGGL(scan_kernel, dim3(BB), dim3(DI), 0, stream,
                               delta, u, dbc, xz, alog_l, Dvec_l, y);
        }
        // h += y @ opw^T   (M=3584, N=256, K=512)
        {
            dim3 grid((DM + 31) / 32, (NTOK + 31) / 32);
            hipLaunchKernelGGL((gemm_nt<2>), grid, blk, 0, stream,
                               y, DI, opw_l, nullptr, h, NTOK, DM, DI);
        }
    }

    // pooled mean + classifier
    hipLaunchKernelGGL(pool_classifier_kernel, dim3(BB), dim3(DM), 0, stream,
                       h, clsw, out);
}

// Round 2
// 853.519 us; speedup vs baseline: 1.3716x; 1.3716x over previous
//
#include <hip/hip_runtime.h>
#include <hip/hip_bf16.h>
#include <cstdint>

#define BB 128
#define LL 28
#define FF 28
#define DM 256
#define DI 512
#define DS 16
#define DR 16
#define KK 3
#define NLAYER 5
#define NOUT 10
#define NTOK (BB * LL)   // 3584

__device__ __forceinline__ float sigmoidf_(float x) { return 1.0f / (1.0f + __expf(-x)); }
__device__ __forceinline__ float siluf_(float x) { return x * sigmoidf_(x); }
__device__ __forceinline__ float softplusf_(float x) {
    return (x > 20.0f) ? x : log1pf(expf(x));
}

// C[M,N] = epilogue( A[M,lda] @ W[N,K]^T )
// Tiles: BM=16*TM, BN=16*TN, BK=16. 256 threads as 16x16; each thread owns a
// contiguous TM x TN output sub-tile -> LDS reads are float4-able.
// EPI 0: C = AB      EPI 2: C += AB (residual, in-place)
template <int TM, int TN, int EPI>
__global__ __launch_bounds__(256) void gemm_nt(const float* __restrict__ A, int lda,
                                               const float* __restrict__ W,
                                               float* __restrict__ C,
                                               int M, int N, int K) {
    constexpr int BM = 16 * TM;
    constexpr int BN = 16 * TN;
    __shared__ float As[16][BM + 4];
    __shared__ float Ws[16][BN + 4];

    const int tid = threadIdx.x;
    const int kk = tid & 15;     // k within tile (for loads)
    const int row = tid >> 4;    // row-pass index (for loads)
    const int tx = tid & 15;     // n-thread
    const int ty = tid >> 4;     // m-thread
    const int bm = blockIdx.y * BM;
    const int bn = blockIdx.x * BN;

    float acc[TM][TN];
    #pragma unroll
    for (int i = 0; i < TM; ++i)
        #pragma unroll
        for (int j = 0; j < TN; ++j) acc[i][j] = 0.f;

    for (int k0 = 0; k0 < K; k0 += 16) {
        const int k = k0 + kk;
        const bool kok = (k < K);
        #pragma unroll
        for (int r = 0; r < TM; ++r) {
            int m = bm + r * 16 + row;
            As[kk][r * 16 + row] = kok ? A[(size_t)m * lda + k] : 0.f;
        }
        #pragma unroll
        for (int r = 0; r < TN; ++r) {
            int n = bn + r * 16 + row;
            Ws[kk][r * 16 + row] = kok ? W[(size_t)n * K + k] : 0.f;
        }
        __syncthreads();
        #pragma unroll
        for (int k2 = 0; k2 < 16; ++k2) {
            float a[TM], b[TN];
            #pragma unroll
            for (int i = 0; i < TM; ++i) a[i] = As[k2][ty * TM + i];
            #pragma unroll
            for (int j = 0; j < TN; ++j) b[j] = Ws[k2][tx * TN + j];
            #pragma unroll
            for (int i = 0; i < TM; ++i)
                #pragma unroll
                for (int j = 0; j < TN; ++j) acc[i][j] += a[i] * b[j];
        }
        __syncthreads();
    }

    #pragma unroll
    for (int i = 0; i < TM; ++i) {
        const int m = bm + ty * TM + i;
        #pragma unroll
        for (int j = 0; j < TN; ++j) {
            const int n = bn + tx * TN + j;
            float v = acc[i][j];
            if (EPI == 2) v += C[(size_t)m * N + n];
            C[(size_t)m * N + n] = v;
        }
    }
}

// u[m, di] = silu( causal_depthwise_conv3(xb)[m,di] + cb[di] ),  xb = xz[:, :DI]
__global__ void conv_silu_kernel(const float* __restrict__ xz,
                                 const float* __restrict__ cw,   // [DI, K]
                                 const float* __restrict__ cb,   // [DI]
                                 float* __restrict__ u) {
    int idx = blockIdx.x * 256 + threadIdx.x;
    if (idx >= NTOK * DI) return;
    int di = idx & (DI - 1);
    int m = idx >> 9;
    int l = m % LL;
    int b = m / LL;
    float acc = cb[di];
    #pragma unroll
    for (int k = 0; k < KK; ++k) {
        int lsrc = l + k - (KK - 1);
        if (lsrc >= 0) {
            acc += xz[(size_t)(b * LL + lsrc) * (2 * DI) + di] * cw[di * KK + k];
        }
    }
    u[(size_t)m * DI + di] = siluf_(acc);
}

// Selective scan with fused dt_proj (delta = softplus(dt@dtw^T + dtb)) and
// fused (y + u*D)*silu(z) epilogue. Grid: (BB, 2) blocks x 256 threads.
__global__ __launch_bounds__(256) void scan_kernel(const float* __restrict__ u,    // [NTOK, DI]
                            const float* __restrict__ dbc,   // [NTOK, DR+2*DS]
                            const float* __restrict__ xz,    // [NTOK, 2*DI]
                            const float* __restrict__ dtw,   // [DI, DR]
                            const float* __restrict__ dtb,   // [DI]
                            const float* __restrict__ A_log, // [DI, DS]
                            const float* __restrict__ Dv,    // [DI]
                            float* __restrict__ y) {         // [NTOK, DI]
    const int b = blockIdx.x;
    const int di = blockIdx.y * 256 + threadIdx.x;
    const int t = threadIdx.x;

    float wdt[DR], A[DS], st[DS];
    #pragma unroll
    for (int r = 0; r < DR; ++r) wdt[r] = dtw[di * DR + r];
    #pragma unroll
    for (int s = 0; s < DS; ++s) {
        A[s] = -expf(A_log[di * DS + s]);
        st[s] = 0.f;
    }
    const float dbias = dtb[di];
    const float Dd = Dv[di];

    __shared__ float sm[DR + 2 * DS];   // dt | B | C of current token

    for (int l = 0; l < LL; ++l) {
        const int m = b * LL + l;
        if (t < DR + 2 * DS) sm[t] = dbc[(size_t)m * (DR + 2 * DS) + t];
        __syncthreads();

        float dtv = dbias;
        #pragma unroll
        for (int r = 0; r < DR; ++r) dtv += wdt[r] * sm[r];
        const float d = softplusf_(dtv);

        const float uu = u[(size_t)m * DI + di];
        const float du = d * uu;
        float yv = 0.f;
        #pragma unroll
        for (int s = 0; s < DS; ++s) {
            st[s] = __expf(d * A[s]) * st[s] + du * sm[DR + s];
            yv += st[s] * sm[DR + DS + s];
        }
        const float zz = xz[(size_t)m * (2 * DI) + DI + di];
        y[(size_t)m * DI + di] = (yv + uu * Dd) * siluf_(zz);
        __syncthreads();
    }
}

__global__ void pool_classifier_kernel(const float* __restrict__ h,   // [NTOK, DM]
                                       const float* __restrict__ cls, // [NOUT, DM]
                                       float* __restrict__ out) {     // [BB, NOUT]
    const int b = blockIdx.x;
    const int dm = threadIdx.x;
    __shared__ float pool[DM];
    float p = 0.f;
    for (int l = 0; l < LL; ++l) p += h[(size_t)(b * LL + l) * DM + dm];
    pool[dm] = p * (1.0f / LL);
    __syncthreads();
    if (dm < NOUT) {
        float acc = 0.f;
        for (int k = 0; k < DM; ++k) acc += pool[k] * cls[dm * DM + k];
        out[b * NOUT + dm] = acc;
    }
}

extern "C" void kernel_launch(void* const* d_in, const int* in_sizes, int n_in,
                              void* d_out, int out_size, void* d_ws, size_t ws_size,
                              hipStream_t stream) {
    const float* x       = (const float*)d_in[0];
    const float* ipw     = (const float*)d_in[1];
    const float* inw     = (const float*)d_in[2];
    const float* convw   = (const float*)d_in[3];
    const float* convb   = (const float*)d_in[4];
    const float* xpw     = (const float*)d_in[5];
    const float* dtw     = (const float*)d_in[6];
    const float* dtb     = (const float*)d_in[7];
    const float* alog    = (const float*)d_in[8];
    const float* Dvec    = (const float*)d_in[9];
    const float* opw     = (const float*)d_in[10];
    const float* clsw    = (const float*)d_in[11];
    float* out = (float*)d_out;

    float* ws = (float*)d_ws;
    float* h   = ws;                              // NTOK*DM
    float* xz  = h + (size_t)NTOK * DM;           // NTOK*2*DI
    float* u   = xz + (size_t)NTOK * 2 * DI;      // NTOK*DI
    float* dbc = u + (size_t)NTOK * DI;           // NTOK*48
    float* y   = dbc + (size_t)NTOK * (DR + 2 * DS); // NTOK*DI

    dim3 blk(256);

    // input projection: h = x @ ipw^T   (M=3584, N=256, K=28)
    hipLaunchKernelGGL((gemm_nt<4, 4, 0>), dim3(DM / 64, NTOK / 64), blk, 0, stream,
                       x, FF, ipw, h, NTOK, DM, FF);

    for (int layer = 0; layer < NLAYER; ++layer) {
        const float* inw_l   = inw  + (size_t)layer * 2 * DI * DM;
        const float* convw_l = convw + (size_t)layer * DI * KK;
        const float* convb_l = convb + (size_t)layer * DI;
        const float* xpw_l   = xpw  + (size_t)layer * (DR + 2 * DS) * DI;
        const float* dtw_l   = dtw  + (size_t)layer * DI * DR;
        const float* dtb_l   = dtb  + (size_t)layer * DI;
        const float* alog_l  = alog + (size_t)layer * DI * DS;
        const float* Dvec_l  = Dvec + (size_t)layer * DI;
        const float* opw_l   = opw  + (size_t)layer * DM * DI;

        // xz = h @ inw^T   (M=3584, N=1024, K=256): 64x64 tiles
        hipLaunchKernelGGL((gemm_nt<4, 4, 0>), dim3(2 * DI / 64, NTOK / 64), blk, 0, stream,
                           h, DM, inw_l, xz, NTOK, 2 * DI, DM);

        // u = silu(conv(xb) + cb)
        hipLaunchKernelGGL(conv_silu_kernel, dim3((NTOK * DI) / 256), blk, 0, stream,
                           xz, convw_l, convb_l, u);

        // dbc = u @ xpw^T   (M=3584, N=48, K=512): 32x48 tiles
        hipLaunchKernelGGL((gemm_nt<2, 3, 0>), dim3(1, NTOK / 32), blk, 0, stream,
                           u, DI, xpw_l, dbc, NTOK, DR + 2 * DS, DI);

        // selective scan (fused dt_proj + gating)
        hipLaunchKernelGGL(scan_kernel, dim3(BB, 2), blk, 0, stream,
                           u, dbc, xz, dtw_l, dtb_l, alog_l, Dvec_l, y);

        // h += y @ opw^T   (M=3584, N=256, K=512): 64x32 tiles
        hipLaunchKernelGGL((gemm_nt<4, 2, 2>), dim3(DM / 32, NTOK / 64), blk, 0, stream,
                           y, DI, opw_l, h, NTOK, DM, DI);
    }

    hipLaunchKernelGGL(pool_classifier_kernel, dim3(BB), dim3(DM), 0, stream,
                       h, clsw, out);
}

// Round 3
// 765.733 us; speedup vs baseline: 1.5288x; 1.1146x over previous
//
#include <hip/hip_runtime.h>
#include <hip/hip_bf16.h>
#include <cstdint>

#define BB 128
#define LL 28
#define FF 28
#define DM 256
#define DI 512
#define DS 16
#define DR 16
#define KK 3
#define NLAYER 5
#define NOUT 10
#define NTOK (BB * LL)   // 3584
#define NDBC (DR + 2 * DS)  // 48

__device__ __forceinline__ float sigmoidf_(float x) { return 1.0f / (1.0f + __expf(-x)); }
__device__ __forceinline__ float siluf_(float x) { return x * sigmoidf_(x); }
__device__ __forceinline__ float softplusf_(float x) {
    return (x > 20.0f) ? x : log1pf(expf(x));
}

// C[M,N] = epilogue( A[M,lda] @ W[N,K]^T )
// Tiles: BM=16*TM, BN=16*TN, BK=16. 256 threads as 16x16; each thread owns a
// contiguous TM x TN output sub-tile -> LDS reads are float4-able.
// EPI 0: C = AB      EPI 2: C += AB (residual, in-place)
template <int TM, int TN, int EPI>
__global__ __launch_bounds__(256) void gemm_nt(const float* __restrict__ A, int lda,
                                               const float* __restrict__ W,
                                               float* __restrict__ C,
                                               int M, int N, int K) {
    constexpr int BM = 16 * TM;
    constexpr int BN = 16 * TN;
    __shared__ float As[16][BM + 4];
    __shared__ float Ws[16][BN + 4];

    const int tid = threadIdx.x;
    const int kk = tid & 15;
    const int row = tid >> 4;
    const int tx = tid & 15;
    const int ty = tid >> 4;
    const int bm = blockIdx.y * BM;
    const int bn = blockIdx.x * BN;

    float acc[TM][TN];
    #pragma unroll
    for (int i = 0; i < TM; ++i)
        #pragma unroll
        for (int j = 0; j < TN; ++j) acc[i][j] = 0.f;

    for (int k0 = 0; k0 < K; k0 += 16) {
        const int k = k0 + kk;
        const bool kok = (k < K);
        #pragma unroll
        for (int r = 0; r < TM; ++r) {
            int m = bm + r * 16 + row;
            As[kk][r * 16 + row] = kok ? A[(size_t)m * lda + k] : 0.f;
        }
        #pragma unroll
        for (int r = 0; r < TN; ++r) {
            int n = bn + r * 16 + row;
            Ws[kk][r * 16 + row] = kok ? W[(size_t)n * K + k] : 0.f;
        }
        __syncthreads();
        #pragma unroll
        for (int k2 = 0; k2 < 16; ++k2) {
            float a[TM], b[TN];
            #pragma unroll
            for (int i = 0; i < TM; ++i) a[i] = As[k2][ty * TM + i];
            #pragma unroll
            for (int j = 0; j < TN; ++j) b[j] = Ws[k2][tx * TN + j];
            #pragma unroll
            for (int i = 0; i < TM; ++i)
                #pragma unroll
                for (int j = 0; j < TN; ++j) acc[i][j] += a[i] * b[j];
        }
        __syncthreads();
    }

    #pragma unroll
    for (int i = 0; i < TM; ++i) {
        const int m = bm + ty * TM + i;
        #pragma unroll
        for (int j = 0; j < TN; ++j) {
            const int n = bn + tx * TN + j;
            float v = acc[i][j];
            if (EPI == 2) v += C[(size_t)m * N + n];
            C[(size_t)m * N + n] = v;
        }
    }
}

// u[m, di] = silu( causal_depthwise_conv3(xb)[m,di] + cb[di] ),  xb = xz[:, :DI]
__global__ void conv_silu_kernel(const float* __restrict__ xz,
                                 const float* __restrict__ cw,   // [DI, K]
                                 const float* __restrict__ cb,   // [DI]
                                 float* __restrict__ u) {
    int idx = blockIdx.x * 256 + threadIdx.x;
    if (idx >= NTOK * DI) return;
    int di = idx & (DI - 1);
    int m = idx >> 9;
    int l = m % LL;
    int b = m / LL;
    float acc = cb[di];
    #pragma unroll
    for (int k = 0; k < KK; ++k) {
        int lsrc = l + k - (KK - 1);
        if (lsrc >= 0) {
            acc += xz[(size_t)(b * LL + lsrc) * (2 * DI) + di] * cw[di * KK + k];
        }
    }
    u[(size_t)m * DI + di] = siluf_(acc);
}

// Selective scan with fused dt_proj and fused (y+u*D)*silu(z) epilogue.
// Stall-free body: whole dbc[b] block staged in LDS once; u/z prefetched to
// registers; 28-step loop fully unrolled, no barriers inside.
__global__ __launch_bounds__(256) void scan_kernel(
                            const float* __restrict__ u,     // [NTOK, DI]
                            const float* __restrict__ dbc,   // [NTOK, NDBC]
                            const float* __restrict__ xz,    // [NTOK, 2*DI]
                            const float* __restrict__ dtw,   // [DI, DR]
                            const float* __restrict__ dtb,   // [DI]
                            const float* __restrict__ A_log, // [DI, DS]
                            const float* __restrict__ Dv,    // [DI]
                            float* __restrict__ y) {         // [NTOK, DI]
    const int b = blockIdx.x;
    const int di = blockIdx.y * 256 + threadIdx.x;
    const int t = threadIdx.x;

    __shared__ float sm[LL][NDBC];   // 28 x 48 floats = 5.25 KB

    // one-shot cooperative stage of all dt|B|C rows for this batch
    const float* src = dbc + (size_t)b * LL * NDBC;
    for (int i = t; i < LL * NDBC; i += 256) sm[i / NDBC][i % NDBC] = src[i];

    float wdt[DR], A[DS], st[DS];
    #pragma unroll
    for (int r = 0; r < DR; ++r) wdt[r] = dtw[di * DR + r];
    #pragma unroll
    for (int s = 0; s < DS; ++s) {
        A[s] = -expf(A_log[di * DS + s]);
        st[s] = 0.f;
    }
    const float dbias = dtb[di];
    const float Dd = Dv[di];

    // prefetch u and z rows for this channel (coalesced; all in flight at once)
    float ur[LL], zr[LL];
    #pragma unroll
    for (int l = 0; l < LL; ++l) {
        const int m = b * LL + l;
        ur[l] = u[(size_t)m * DI + di];
        zr[l] = xz[(size_t)m * (2 * DI) + DI + di];
    }
    __syncthreads();

    #pragma unroll
    for (int l = 0; l < LL; ++l) {
        float dtv = dbias;
        #pragma unroll
        for (int r = 0; r < DR; ++r) dtv += wdt[r] * sm[l][r];
        const float d = softplusf_(dtv);

        const float du = d * ur[l];
        float yv = 0.f;
        #pragma unroll
        for (int s = 0; s < DS; ++s) {
            st[s] = __expf(d * A[s]) * st[s] + du * sm[l][DR + s];
            yv += st[s] * sm[l][DR + DS + s];
        }
        y[(size_t)(b * LL + l) * DI + di] = (yv + ur[l] * Dd) * siluf_(zr[l]);
    }
}

__global__ void pool_classifier_kernel(const float* __restrict__ h,   // [NTOK, DM]
                                       const float* __restrict__ cls, // [NOUT, DM]
                                       float* __restrict__ out) {     // [BB, NOUT]
    const int b = blockIdx.x;
    const int dm = threadIdx.x;
    __shared__ float pool[DM];
    float p = 0.f;
    for (int l = 0; l < LL; ++l) p += h[(size_t)(b * LL + l) * DM + dm];
    pool[dm] = p * (1.0f / LL);
    __syncthreads();
    if (dm < NOUT) {
        float acc = 0.f;
        for (int k = 0; k < DM; ++k) acc += pool[k] * cls[dm * DM + k];
        out[b * NOUT + dm] = acc;
    }
}

extern "C" void kernel_launch(void* const* d_in, const int* in_sizes, int n_in,
                              void* d_out, int out_size, void* d_ws, size_t ws_size,
                              hipStream_t stream) {
    const float* x       = (const float*)d_in[0];
    const float* ipw     = (const float*)d_in[1];
    const float* inw     = (const float*)d_in[2];
    const float* convw   = (const float*)d_in[3];
    const float* convb   = (const float*)d_in[4];
    const float* xpw     = (const float*)d_in[5];
    const float* dtw     = (const float*)d_in[6];
    const float* dtb     = (const float*)d_in[7];
    const float* alog    = (const float*)d_in[8];
    const float* Dvec    = (const float*)d_in[9];
    const float* opw     = (const float*)d_in[10];
    const float* clsw    = (const float*)d_in[11];
    float* out = (float*)d_out;

    float* ws = (float*)d_ws;
    float* h   = ws;                              // NTOK*DM
    float* xz  = h + (size_t)NTOK * DM;           // NTOK*2*DI
    float* u   = xz + (size_t)NTOK * 2 * DI;      // NTOK*DI
    float* dbc = u + (size_t)NTOK * DI;           // NTOK*48
    float* y   = dbc + (size_t)NTOK * NDBC;       // NTOK*DI

    dim3 blk(256);

    // input projection: h = x @ ipw^T   (M=3584, N=256, K=28)
    hipLaunchKernelGGL((gemm_nt<4, 4, 0>), dim3(DM / 64, NTOK / 64), blk, 0, stream,
                       x, FF, ipw, h, NTOK, DM, FF);

    for (int layer = 0; layer < NLAYER; ++layer) {
        const float* inw_l   = inw  + (size_t)layer * 2 * DI * DM;
        const float* convw_l = convw + (size_t)layer * DI * KK;
        const float* convb_l = convb + (size_t)layer * DI;
        const float* xpw_l   = xpw  + (size_t)layer * NDBC * DI;
        const float* dtw_l   = dtw  + (size_t)layer * DI * DR;
        const float* dtb_l   = dtb  + (size_t)layer * DI;
        const float* alog_l  = alog + (size_t)layer * DI * DS;
        const float* Dvec_l  = Dvec + (size_t)layer * DI;
        const float* opw_l   = opw  + (size_t)layer * DM * DI;

        // xz = h @ inw^T   (M=3584, N=1024, K=256): 64x64 tiles
        hipLaunchKernelGGL((gemm_nt<4, 4, 0>), dim3(2 * DI / 64, NTOK / 64), blk, 0, stream,
                           h, DM, inw_l, xz, NTOK, 2 * DI, DM);

        // u = silu(conv(xb) + cb)
        hipLaunchKernelGGL(conv_silu_kernel, dim3((NTOK * DI) / 256), blk, 0, stream,
                           xz, convw_l, convb_l, u);

        // dbc = u @ xpw^T   (M=3584, N=48, K=512): 32x48 tiles
        hipLaunchKernelGGL((gemm_nt<2, 3, 0>), dim3(1, NTOK / 32), blk, 0, stream,
                           u, DI, xpw_l, dbc, NTOK, NDBC, DI);

        // selective scan (fused dt_proj + gating)
        hipLaunchKernelGGL(scan_kernel, dim3(BB, 2), blk, 0, stream,
                           u, dbc, xz, dtw_l, dtb_l, alog_l, Dvec_l, y);

        // h += y @ opw^T   (M=3584, N=256, K=512): 64x32 tiles
        hipLaunchKernelGGL((gemm_nt<4, 2, 2>), dim3(DM / 32, NTOK / 64), blk, 0, stream,
                           y, DI, opw_l, h, NTOK, DM, DI);
    }

    hipLaunchKernelGGL(pool_classifier_kernel, dim3(BB), dim3(DM), 0, stream,
                       h, clsw, out);
}